// Round 3
// baseline (215.883 us; speedup 1.0000x reference)
//
#include <hip/hip_runtime.h>
#include <hip/hip_bf16.h>

#define NN 4096
#define KIN 256
#define HF 512
#define NHD 4
#define OF 128
#define JP 4160            // padded hbT row stride (8320 B: non-pow2 channel spread)

typedef __bf16 bf16x8 __attribute__((ext_vector_type(8)));
typedef __bf16 bf16x4 __attribute__((ext_vector_type(4)));
typedef float f32x4 __attribute__((ext_vector_type(4)));
typedef _Float16 f16x4 __attribute__((ext_vector_type(4)));

// ---------------- K0: WT[c][k] = (bf16)W[k][c], LDS-tiled ----------------
__global__ __launch_bounds__(256) void k_transpose_w(const float* __restrict__ W,
                                                     __bf16* __restrict__ WT) {
    __shared__ __bf16 tl[64][65];
    int k0 = blockIdx.x * 64, c0 = blockIdx.y * 64;
    #pragma unroll
    for (int it = 0; it < 16; ++it) {
        int idx = it * 256 + threadIdx.x;
        int kk = idx >> 6, cc = idx & 63;
        tl[kk][cc] = (__bf16)W[(size_t)(k0 + kk) * HF + c0 + cc];
    }
    __syncthreads();
    #pragma unroll
    for (int it = 0; it < 16; ++it) {
        int idx = it * 256 + threadIdx.x;
        int cc = idx >> 6, kk = idx & 63;
        WT[(size_t)(c0 + cc) * KIN + k0 + kk] = tl[kk][cc];
    }
}

// ------- K1: gemm (hbT) + fused ci/cj. Block = 16 nodes x all 512 c. -------
// 8 waves, wave w: c0 = w*64. A = x rows (node), B = WT rows (c).
__global__ __launch_bounds__(512) void k_gemm_h(const float* __restrict__ x,
                                                const __bf16* __restrict__ WT,
                                                const float* __restrict__ ai,
                                                const float* __restrict__ aj,
                                                __bf16* __restrict__ hbT,
                                                float* __restrict__ ci,
                                                float* __restrict__ cj) {
    __shared__ float credi[8][16], credj[8][16];
    int tid = threadIdx.x, lane = tid & 63, w = tid >> 6;
    int r = lane & 15, q = lane >> 4;
    int m0 = blockIdx.x * 16;
    int c0 = w * 64;
    f32x4 acc[4];
    #pragma unroll
    for (int nt = 0; nt < 4; ++nt) acc[nt] = (f32x4){0.f, 0.f, 0.f, 0.f};
    const float* xp = x + (size_t)(m0 + r) * KIN + q * 8;
    #pragma unroll
    for (int kk = 0; kk < 8; ++kk) {
        float4 xa = *(const float4*)(xp + kk * 32);
        float4 xb = *(const float4*)(xp + kk * 32 + 4);
        bf16x8 af;
        af[0] = (__bf16)xa.x; af[1] = (__bf16)xa.y; af[2] = (__bf16)xa.z; af[3] = (__bf16)xa.w;
        af[4] = (__bf16)xb.x; af[5] = (__bf16)xb.y; af[6] = (__bf16)xb.z; af[7] = (__bf16)xb.w;
        #pragma unroll
        for (int nt = 0; nt < 4; ++nt) {
            bf16x8 bf = *(const bf16x8*)(WT + (size_t)(c0 + nt * 16 + r) * KIN + kk * 32 + q * 8);
            acc[nt] = __builtin_amdgcn_mfma_f32_16x16x32_bf16(af, bf, acc[nt], 0, 0, 0);
        }
    }
    float pi[4] = {0.f, 0.f, 0.f, 0.f}, pj[4] = {0.f, 0.f, 0.f, 0.f};
    #pragma unroll
    for (int nt = 0; nt < 4; ++nt) {
        int c = c0 + nt * 16 + r;
        float av = ai[c], jv = aj[c];
        bf16x4 o;
        #pragma unroll
        for (int e = 0; e < 4; ++e) {
            o[e] = (__bf16)acc[nt][e];
            pi[e] += av * acc[nt][e];
            pj[e] += jv * acc[nt][e];
        }
        *(bf16x4*)(hbT + (size_t)c * JP + m0 + q * 4) = o;
    }
    #pragma unroll
    for (int off = 1; off < 16; off <<= 1)
        #pragma unroll
        for (int e = 0; e < 4; ++e) {
            pi[e] += __shfl_xor(pi[e], off);
            pj[e] += __shfl_xor(pj[e], off);
        }
    if (r == 0)
        #pragma unroll
        for (int e = 0; e < 4; ++e) {
            credi[w][q * 4 + e] = pi[e];
            credj[w][q * 4 + e] = pj[e];
        }
    __syncthreads();
    if (tid < 64) {                       // t = h*16 + node-local
        int h = tid >> 4, nl = tid & 15;
        ci[h * NN + m0 + nl] = credi[2 * h][nl] + credi[2 * h + 1][nl];
    } else if (tid < 128) {
        int t = tid - 64;
        int h = t >> 4, nl = t & 15;
        cj[h * NN + m0 + nl] = credj[2 * h][nl] + credj[2 * h + 1][nl];
    }
}

// ---------------- K3: fused attention, zero LDS, max-MLP scheduling ----------------
// grid 256: js = bid&3 (XCD-pinned V slice), i-tile = bid>>2 (64 rows).
// 512 thr = 8 waves: h = w&3, rg = w>>2 (32 rows each, 2 MFMA row-groups g).
// Per chunk (load-early / use-late, T14):
//   1. issue ALL 16 V-fragment loads (vb regs, MLP=16) -> latency hidden by VALU phase
//   2. VALU ks=0 (consumes pa[0,1,4,5]/pc[0,1]) -> re-issue those 6 loads for c+1
//   3. VALU ks=1 (consumes pa[2,3,6,7]/pc[2,3]) -> re-issue those 6 loads for c+1
//      (adj prefetch gets ~half VALU + full MFMA phase of latency cover)
//   4. MFMA phase consumes vb; compiler emits counted vmcnt (12 adj/cj in flight)
// No LDS, no barriers; waves fully independent.
__global__ __launch_bounds__(512, 2) void k_attn(const float* __restrict__ adj,
                                                 const __bf16* __restrict__ hbT,
                                                 const float* __restrict__ ci,
                                                 const float* __restrict__ cj,
                                                 _Float16* __restrict__ num,
                                                 float* __restrict__ den) {
    int tid = threadIdx.x, lane = tid & 63, w = tid >> 6;
    int h = w & 3, rg = w >> 2;
    int m = lane & 15, q = lane >> 4;
    int bid = blockIdx.x;
    int js = bid & 3, i0 = (bid >> 2) * 64, jb = js * 1024;

    // per-lane fragment base pointers
    const float* ap0 = adj + (size_t)(i0 + rg * 32 + m) * NN + jb + q * 8;       // g=0 row
    const float* ap1 = ap0 + (size_t)16 * NN;                                    // g=1 row
    const float* cjp = cj + (size_t)h * NN + jb + q * 8;
    const __bf16* vp = hbT + (size_t)(h * OF + m) * JP + jb + q * 8;

    float civ0 = ci[h * NN + i0 + rg * 32 + m];
    float civ1 = ci[h * NN + i0 + rg * 32 + 16 + m];

    f32x4 acc[2][8];
    #pragma unroll
    for (int g = 0; g < 2; ++g)
        #pragma unroll
        for (int nt = 0; nt < 8; ++nt) acc[g][nt] = (f32x4){0.f, 0.f, 0.f, 0.f};
    float den0 = 0.f, den1 = 0.f;

    // prefetch chunk 0: adj frags (8xfloat4) + cj frags (4xfloat4)
    // pa layout: [g*4 + ks*2 + half]
    float4 pa[8], pc[4];
    pa[0] = *(const float4*)(ap0);
    pa[1] = *(const float4*)(ap0 + 4);
    pa[2] = *(const float4*)(ap0 + 32);
    pa[3] = *(const float4*)(ap0 + 36);
    pa[4] = *(const float4*)(ap1);
    pa[5] = *(const float4*)(ap1 + 4);
    pa[6] = *(const float4*)(ap1 + 32);
    pa[7] = *(const float4*)(ap1 + 36);
    pc[0] = *(const float4*)(cjp);
    pc[1] = *(const float4*)(cjp + 4);
    pc[2] = *(const float4*)(cjp + 32);
    pc[3] = *(const float4*)(cjp + 36);

    for (int c = 0; c < 16; ++c) {
        // ---- 1. issue ALL V loads for this chunk (independent, MLP=16) ----
        bf16x8 vb[2][8];
        #pragma unroll
        for (int ks = 0; ks < 2; ++ks)
            #pragma unroll
            for (int nt = 0; nt < 8; ++nt)
                vb[ks][nt] = *(const bf16x8*)(vp + (size_t)(nt * 16) * JP + c * 64 + ks * 32);

        bf16x8 af0[2], af1[2];
        int off = (c + 1) * 64;

        // ---- 2. VALU ks=0 (covers V latency), then re-issue its adj/cj regs ----
        {
            float ccv[8];
            ccv[0] = pc[0].x; ccv[1] = pc[0].y; ccv[2] = pc[0].z; ccv[3] = pc[0].w;
            ccv[4] = pc[1].x; ccv[5] = pc[1].y; ccv[6] = pc[1].z; ccv[7] = pc[1].w;
            float aa0[8], aa1[8];
            aa0[0] = pa[0].x; aa0[1] = pa[0].y; aa0[2] = pa[0].z; aa0[3] = pa[0].w;
            aa0[4] = pa[1].x; aa0[5] = pa[1].y; aa0[6] = pa[1].z; aa0[7] = pa[1].w;
            aa1[0] = pa[4].x; aa1[1] = pa[4].y; aa1[2] = pa[4].z; aa1[3] = pa[4].w;
            aa1[4] = pa[5].x; aa1[5] = pa[5].y; aa1[6] = pa[5].z; aa1[7] = pa[5].w;
            #pragma unroll
            for (int u = 0; u < 8; ++u) {
                float a = aa0[u];
                float s = civ0 + ccv[u];
                s = fmaxf(s, s * 0.2f);     // leaky_relu
                s *= a;
                float p = __expf(s);        // s in ~[-4,4]: shift-free softmax safe
                den0 += p;
                af0[0][u] = (__bf16)(p * a);
            }
            #pragma unroll
            for (int u = 0; u < 8; ++u) {
                float a = aa1[u];
                float s = civ1 + ccv[u];
                s = fmaxf(s, s * 0.2f);
                s *= a;
                float p = __expf(s);
                den1 += p;
                af1[0][u] = (__bf16)(p * a);
            }
        }
        if (c + 1 < 16) {                   // prefetch the regs ks=0 just freed
            pa[0] = *(const float4*)(ap0 + off);
            pa[1] = *(const float4*)(ap0 + off + 4);
            pa[4] = *(const float4*)(ap1 + off);
            pa[5] = *(const float4*)(ap1 + off + 4);
            pc[0] = *(const float4*)(cjp + off);
            pc[1] = *(const float4*)(cjp + off + 4);
        }

        // ---- 3. VALU ks=1, then re-issue its adj/cj regs ----
        {
            float ccv[8];
            ccv[0] = pc[2].x; ccv[1] = pc[2].y; ccv[2] = pc[2].z; ccv[3] = pc[2].w;
            ccv[4] = pc[3].x; ccv[5] = pc[3].y; ccv[6] = pc[3].z; ccv[7] = pc[3].w;
            float aa0[8], aa1[8];
            aa0[0] = pa[2].x; aa0[1] = pa[2].y; aa0[2] = pa[2].z; aa0[3] = pa[2].w;
            aa0[4] = pa[3].x; aa0[5] = pa[3].y; aa0[6] = pa[3].z; aa0[7] = pa[3].w;
            aa1[0] = pa[6].x; aa1[1] = pa[6].y; aa1[2] = pa[6].z; aa1[3] = pa[6].w;
            aa1[4] = pa[7].x; aa1[5] = pa[7].y; aa1[6] = pa[7].z; aa1[7] = pa[7].w;
            #pragma unroll
            for (int u = 0; u < 8; ++u) {
                float a = aa0[u];
                float s = civ0 + ccv[u];
                s = fmaxf(s, s * 0.2f);
                s *= a;
                float p = __expf(s);
                den0 += p;
                af0[1][u] = (__bf16)(p * a);
            }
            #pragma unroll
            for (int u = 0; u < 8; ++u) {
                float a = aa1[u];
                float s = civ1 + ccv[u];
                s = fmaxf(s, s * 0.2f);
                s *= a;
                float p = __expf(s);
                den1 += p;
                af1[1][u] = (__bf16)(p * a);
            }
        }
        if (c + 1 < 16) {
            pa[2] = *(const float4*)(ap0 + off + 32);
            pa[3] = *(const float4*)(ap0 + off + 36);
            pa[6] = *(const float4*)(ap1 + off + 32);
            pa[7] = *(const float4*)(ap1 + off + 36);
            pc[2] = *(const float4*)(cjp + off + 32);
            pc[3] = *(const float4*)(cjp + off + 36);
        }

        // ---- 4. MFMA phase: V fragments already in vb registers ----
        #pragma unroll
        for (int ks = 0; ks < 2; ++ks)
            #pragma unroll
            for (int nt = 0; nt < 8; ++nt) {
                acc[0][nt] = __builtin_amdgcn_mfma_f32_16x16x32_bf16(af0[ks], vb[ks][nt], acc[0][nt], 0, 0, 0);
                acc[1][nt] = __builtin_amdgcn_mfma_f32_16x16x32_bf16(af1[ks], vb[ks][nt], acc[1][nt], 0, 0, 0);
            }
    }
    // den over q-partitions (j mod 32): lanes {m, m+16, m+32, m+48}
    den0 += __shfl_xor(den0, 16); den0 += __shfl_xor(den0, 32);
    den1 += __shfl_xor(den1, 16); den1 += __shfl_xor(den1, 32);
    if (lane < 16) {
        float* dp = den + ((size_t)js * NHD + h) * NN + i0 + rg * 32;
        dp[lane] = den0;
        dp[16 + lane] = den1;
    }
    // num partials (fp16): C/D row = q*4+reg (i-local), col = nt*16+m (f)
    #pragma unroll
    for (int g = 0; g < 2; ++g)
        #pragma unroll
        for (int nt = 0; nt < 8; ++nt)
            #pragma unroll
            for (int reg = 0; reg < 4; ++reg) {
                int i = i0 + rg * 32 + g * 16 + q * 4 + reg;
                num[((size_t)js * NN + i) * HF + h * OF + nt * 16 + m] =
                    (_Float16)acc[g][nt][reg];
            }
}

// ---------------- K4: reduce js partials, divide, +bias, fp32 out ---------
__global__ __launch_bounds__(256) void k_reduce(const _Float16* __restrict__ num,
                                                const float* __restrict__ den,
                                                const float* __restrict__ bias,
                                                float* __restrict__ out) {
    int g = blockIdx.x * 256 + threadIdx.x;    // NN*HF/4 groups
    int i = g >> 7, c4 = (g & 127) << 2;
    int h = c4 >> 7;
    float s0 = 0.f, s1 = 0.f, s2 = 0.f, s3 = 0.f, d = 0.f;
    #pragma unroll
    for (int js = 0; js < 4; ++js) {
        f16x4 v = *(const f16x4*)(num + ((size_t)js * NN + i) * HF + c4);
        s0 += (float)v[0]; s1 += (float)v[1]; s2 += (float)v[2]; s3 += (float)v[3];
        d += den[((size_t)js * NHD + h) * NN + i];
    }
    float inv = 1.0f / d;
    float4 b = *(const float4*)(bias + c4);
    float4 o;
    o.x = s0 * inv + b.x; o.y = s1 * inv + b.y;
    o.z = s2 * inv + b.z; o.w = s3 * inv + b.w;
    *(float4*)(out + (size_t)i * HF + c4) = o;
}

extern "C" void kernel_launch(void* const* d_in, const int* in_sizes, int n_in,
                              void* d_out, int out_size, void* d_ws, size_t ws_size,
                              hipStream_t stream) {
    const float* x    = (const float*)d_in[0];
    const float* adj  = (const float*)d_in[1];
    const float* W    = (const float*)d_in[2];
    const float* ai   = (const float*)d_in[3];
    const float* aj   = (const float*)d_in[4];
    const float* bias = (const float*)d_in[5];
    float* out = (float*)d_out;

    char* ws = (char*)d_ws;
    __bf16*   hbT = (__bf16*)(ws);                       // 4,259,840 B
    float*    ci  = (float*)(ws + 4456448);              // 64 KB
    float*    cj  = (float*)(ws + 4456448 + 65536);      // 64 KB
    float*    den = (float*)(ws + 4587520);              // 256 KB
    __bf16*   WT  = (__bf16*)(ws + 4980736);             // 256 KB
    _Float16* num = (_Float16*)(ws + 5242880);           // 16 MB -> ends ~20.25 MB

    k_transpose_w<<<dim3(4, 8), 256, 0, stream>>>(W, WT);
    k_gemm_h<<<256, 512, 0, stream>>>(x, WT, ai, aj, hbT, ci, cj);
    k_attn<<<256, 512, 0, stream>>>(adj, hbT, ci, cj, num, den);
    k_reduce<<<2048, 256, 0, stream>>>(num, den, bias, out);
}

// Round 4
// 215.393 us; speedup vs baseline: 1.0023x; 1.0023x over previous
//
#include <hip/hip_runtime.h>
#include <hip/hip_bf16.h>

#define NN 4096
#define KIN 256
#define HF 512
#define NHD 4
#define OF 128
#define JP 4160            // padded hbT row stride (8320 B: non-pow2 channel spread)

typedef __bf16 bf16x8 __attribute__((ext_vector_type(8)));
typedef __bf16 bf16x4 __attribute__((ext_vector_type(4)));
typedef float f32x4 __attribute__((ext_vector_type(4)));
typedef _Float16 f16x4 __attribute__((ext_vector_type(4)));

// ---------------- K0: WT[c][k] = (bf16)W[k][c], LDS-tiled ----------------
__global__ __launch_bounds__(256) void k_transpose_w(const float* __restrict__ W,
                                                     __bf16* __restrict__ WT) {
    __shared__ __bf16 tl[64][65];
    int k0 = blockIdx.x * 64, c0 = blockIdx.y * 64;
    #pragma unroll
    for (int it = 0; it < 16; ++it) {
        int idx = it * 256 + threadIdx.x;
        int kk = idx >> 6, cc = idx & 63;
        tl[kk][cc] = (__bf16)W[(size_t)(k0 + kk) * HF + c0 + cc];
    }
    __syncthreads();
    #pragma unroll
    for (int it = 0; it < 16; ++it) {
        int idx = it * 256 + threadIdx.x;
        int cc = idx >> 6, kk = idx & 63;
        WT[(size_t)(c0 + cc) * KIN + k0 + kk] = tl[kk][cc];
    }
}

// ------- K1: gemm (hbT) + fused ci/cj. Block = 16 nodes x all 512 c. -------
// 8 waves, wave w: c0 = w*64. A = x rows (node), B = WT rows (c).
// opad: force 1 block/CU so the 256-block grid must spread across all 256 CUs
// (at VGPR<=128 capacity is 2 blocks/CU; greedy packing would idle half the CUs).
__global__ __launch_bounds__(512) void k_gemm_h(const float* __restrict__ x,
                                                const __bf16* __restrict__ WT,
                                                const float* __restrict__ ai,
                                                const float* __restrict__ aj,
                                                __bf16* __restrict__ hbT,
                                                float* __restrict__ ci,
                                                float* __restrict__ cj) {
    __shared__ float credi[8][16], credj[8][16];
    __shared__ char opad[86016];
    int tid = threadIdx.x, lane = tid & 63, w = tid >> 6;
    if (tid == 0) { volatile char* p = opad; p[0] = 1; }   // keep allocation live
    int r = lane & 15, q = lane >> 4;
    int m0 = blockIdx.x * 16;
    int c0 = w * 64;
    f32x4 acc[4];
    #pragma unroll
    for (int nt = 0; nt < 4; ++nt) acc[nt] = (f32x4){0.f, 0.f, 0.f, 0.f};
    const float* xp = x + (size_t)(m0 + r) * KIN + q * 8;
    #pragma unroll
    for (int kk = 0; kk < 8; ++kk) {
        float4 xa = *(const float4*)(xp + kk * 32);
        float4 xb = *(const float4*)(xp + kk * 32 + 4);
        bf16x8 af;
        af[0] = (__bf16)xa.x; af[1] = (__bf16)xa.y; af[2] = (__bf16)xa.z; af[3] = (__bf16)xa.w;
        af[4] = (__bf16)xb.x; af[5] = (__bf16)xb.y; af[6] = (__bf16)xb.z; af[7] = (__bf16)xb.w;
        #pragma unroll
        for (int nt = 0; nt < 4; ++nt) {
            bf16x8 bf = *(const bf16x8*)(WT + (size_t)(c0 + nt * 16 + r) * KIN + kk * 32 + q * 8);
            acc[nt] = __builtin_amdgcn_mfma_f32_16x16x32_bf16(af, bf, acc[nt], 0, 0, 0);
        }
    }
    float pi[4] = {0.f, 0.f, 0.f, 0.f}, pj[4] = {0.f, 0.f, 0.f, 0.f};
    #pragma unroll
    for (int nt = 0; nt < 4; ++nt) {
        int c = c0 + nt * 16 + r;
        float av = ai[c], jv = aj[c];
        bf16x4 o;
        #pragma unroll
        for (int e = 0; e < 4; ++e) {
            o[e] = (__bf16)acc[nt][e];
            pi[e] += av * acc[nt][e];
            pj[e] += jv * acc[nt][e];
        }
        *(bf16x4*)(hbT + (size_t)c * JP + m0 + q * 4) = o;
    }
    #pragma unroll
    for (int off = 1; off < 16; off <<= 1)
        #pragma unroll
        for (int e = 0; e < 4; ++e) {
            pi[e] += __shfl_xor(pi[e], off);
            pj[e] += __shfl_xor(pj[e], off);
        }
    if (r == 0)
        #pragma unroll
        for (int e = 0; e < 4; ++e) {
            credi[w][q * 4 + e] = pi[e];
            credj[w][q * 4 + e] = pj[e];
        }
    __syncthreads();
    if (tid < 64) {                       // t = h*16 + node-local
        int h = tid >> 4, nl = tid & 15;
        ci[h * NN + m0 + nl] = credi[2 * h][nl] + credi[2 * h + 1][nl];
    } else if (tid < 128) {
        int t = tid - 64;
        int h = t >> 4, nl = t & 15;
        cj[h * NN + m0 + nl] = credj[2 * h][nl] + credj[2 * h + 1][nl];
    }
}

// ---------------- K3: fused attention, zero LDS use, max-MLP scheduling ----------------
// grid 256: js = bid&3 (XCD-pinned V slice), i-tile = bid>>2 (64 rows).
// 512 thr = 8 waves: h = w&3, rg = w>>2 (32 rows each, 2 MFMA row-groups g).
// ROUND-4 EXPERIMENT: opad (84 KB dummy LDS) caps residency at 1 block/CU.
// At VGPR=96 the HW otherwise allows 2 blocks/CU; a greedily-packed 256-block
// grid then lands on only 128 CUs (measured 16.5K cy/chunk vs <=4.4K cy/chunk
// from per-wave issue+latency accounting -- a ~4x gap only CU-idling explains).
// Forcing 1 block/CU makes the dispatcher spread 256 blocks over 256 CUs.
__global__ __launch_bounds__(512, 2) void k_attn(const float* __restrict__ adj,
                                                 const __bf16* __restrict__ hbT,
                                                 const float* __restrict__ ci,
                                                 const float* __restrict__ cj,
                                                 _Float16* __restrict__ num,
                                                 float* __restrict__ den) {
    __shared__ char opad[86016];
    int tid = threadIdx.x, lane = tid & 63, w = tid >> 6;
    if (tid == 0) { volatile char* p = opad; p[0] = 1; }   // keep allocation live
    int h = w & 3, rg = w >> 2;
    int m = lane & 15, q = lane >> 4;
    int bid = blockIdx.x;
    int js = bid & 3, i0 = (bid >> 2) * 64, jb = js * 1024;

    // per-lane fragment base pointers
    const float* ap0 = adj + (size_t)(i0 + rg * 32 + m) * NN + jb + q * 8;       // g=0 row
    const float* ap1 = ap0 + (size_t)16 * NN;                                    // g=1 row
    const float* cjp = cj + (size_t)h * NN + jb + q * 8;
    const __bf16* vp = hbT + (size_t)(h * OF + m) * JP + jb + q * 8;

    float civ0 = ci[h * NN + i0 + rg * 32 + m];
    float civ1 = ci[h * NN + i0 + rg * 32 + 16 + m];

    f32x4 acc[2][8];
    #pragma unroll
    for (int g = 0; g < 2; ++g)
        #pragma unroll
        for (int nt = 0; nt < 8; ++nt) acc[g][nt] = (f32x4){0.f, 0.f, 0.f, 0.f};
    float den0 = 0.f, den1 = 0.f;

    // prefetch chunk 0: adj frags (8xfloat4) + cj frags (4xfloat4)
    // pa layout: [g*4 + ks*2 + half]
    float4 pa[8], pc[4];
    pa[0] = *(const float4*)(ap0);
    pa[1] = *(const float4*)(ap0 + 4);
    pa[2] = *(const float4*)(ap0 + 32);
    pa[3] = *(const float4*)(ap0 + 36);
    pa[4] = *(const float4*)(ap1);
    pa[5] = *(const float4*)(ap1 + 4);
    pa[6] = *(const float4*)(ap1 + 32);
    pa[7] = *(const float4*)(ap1 + 36);
    pc[0] = *(const float4*)(cjp);
    pc[1] = *(const float4*)(cjp + 4);
    pc[2] = *(const float4*)(cjp + 32);
    pc[3] = *(const float4*)(cjp + 36);

    for (int c = 0; c < 16; ++c) {
        // ---- 1. issue ALL V loads for this chunk (independent, MLP=16) ----
        bf16x8 vb[2][8];
        #pragma unroll
        for (int ks = 0; ks < 2; ++ks)
            #pragma unroll
            for (int nt = 0; nt < 8; ++nt)
                vb[ks][nt] = *(const bf16x8*)(vp + (size_t)(nt * 16) * JP + c * 64 + ks * 32);

        bf16x8 af0[2], af1[2];
        int off = (c + 1) * 64;

        // ---- 2. VALU ks=0 (covers V latency), then re-issue its adj/cj regs ----
        {
            float ccv[8];
            ccv[0] = pc[0].x; ccv[1] = pc[0].y; ccv[2] = pc[0].z; ccv[3] = pc[0].w;
            ccv[4] = pc[1].x; ccv[5] = pc[1].y; ccv[6] = pc[1].z; ccv[7] = pc[1].w;
            float aa0[8], aa1[8];
            aa0[0] = pa[0].x; aa0[1] = pa[0].y; aa0[2] = pa[0].z; aa0[3] = pa[0].w;
            aa0[4] = pa[1].x; aa0[5] = pa[1].y; aa0[6] = pa[1].z; aa0[7] = pa[1].w;
            aa1[0] = pa[4].x; aa1[1] = pa[4].y; aa1[2] = pa[4].z; aa1[3] = pa[4].w;
            aa1[4] = pa[5].x; aa1[5] = pa[5].y; aa1[6] = pa[5].z; aa1[7] = pa[5].w;
            #pragma unroll
            for (int u = 0; u < 8; ++u) {
                float a = aa0[u];
                float s = civ0 + ccv[u];
                s = fmaxf(s, s * 0.2f);     // leaky_relu
                s *= a;
                float p = __expf(s);        // s in ~[-4,4]: shift-free softmax safe
                den0 += p;
                af0[0][u] = (__bf16)(p * a);
            }
            #pragma unroll
            for (int u = 0; u < 8; ++u) {
                float a = aa1[u];
                float s = civ1 + ccv[u];
                s = fmaxf(s, s * 0.2f);
                s *= a;
                float p = __expf(s);
                den1 += p;
                af1[0][u] = (__bf16)(p * a);
            }
        }
        if (c + 1 < 16) {                   // prefetch the regs ks=0 just freed
            pa[0] = *(const float4*)(ap0 + off);
            pa[1] = *(const float4*)(ap0 + off + 4);
            pa[4] = *(const float4*)(ap1 + off);
            pa[5] = *(const float4*)(ap1 + off + 4);
            pc[0] = *(const float4*)(cjp + off);
            pc[1] = *(const float4*)(cjp + off + 4);
        }

        // ---- 3. VALU ks=1, then re-issue its adj/cj regs ----
        {
            float ccv[8];
            ccv[0] = pc[2].x; ccv[1] = pc[2].y; ccv[2] = pc[2].z; ccv[3] = pc[2].w;
            ccv[4] = pc[3].x; ccv[5] = pc[3].y; ccv[6] = pc[3].z; ccv[7] = pc[3].w;
            float aa0[8], aa1[8];
            aa0[0] = pa[2].x; aa0[1] = pa[2].y; aa0[2] = pa[2].z; aa0[3] = pa[2].w;
            aa0[4] = pa[3].x; aa0[5] = pa[3].y; aa0[6] = pa[3].z; aa0[7] = pa[3].w;
            aa1[0] = pa[6].x; aa1[1] = pa[6].y; aa1[2] = pa[6].z; aa1[3] = pa[6].w;
            aa1[4] = pa[7].x; aa1[5] = pa[7].y; aa1[6] = pa[7].z; aa1[7] = pa[7].w;
            #pragma unroll
            for (int u = 0; u < 8; ++u) {
                float a = aa0[u];
                float s = civ0 + ccv[u];
                s = fmaxf(s, s * 0.2f);
                s *= a;
                float p = __expf(s);
                den0 += p;
                af0[1][u] = (__bf16)(p * a);
            }
            #pragma unroll
            for (int u = 0; u < 8; ++u) {
                float a = aa1[u];
                float s = civ1 + ccv[u];
                s = fmaxf(s, s * 0.2f);
                s *= a;
                float p = __expf(s);
                den1 += p;
                af1[1][u] = (__bf16)(p * a);
            }
        }
        if (c + 1 < 16) {
            pa[2] = *(const float4*)(ap0 + off + 32);
            pa[3] = *(const float4*)(ap0 + off + 36);
            pa[6] = *(const float4*)(ap1 + off + 32);
            pa[7] = *(const float4*)(ap1 + off + 36);
            pc[2] = *(const float4*)(cjp + off + 32);
            pc[3] = *(const float4*)(cjp + off + 36);
        }

        // ---- 4. MFMA phase: V fragments already in vb registers ----
        #pragma unroll
        for (int ks = 0; ks < 2; ++ks)
            #pragma unroll
            for (int nt = 0; nt < 8; ++nt) {
                acc[0][nt] = __builtin_amdgcn_mfma_f32_16x16x32_bf16(af0[ks], vb[ks][nt], acc[0][nt], 0, 0, 0);
                acc[1][nt] = __builtin_amdgcn_mfma_f32_16x16x32_bf16(af1[ks], vb[ks][nt], acc[1][nt], 0, 0, 0);
            }
    }
    // den over q-partitions (j mod 32): lanes {m, m+16, m+32, m+48}
    den0 += __shfl_xor(den0, 16); den0 += __shfl_xor(den0, 32);
    den1 += __shfl_xor(den1, 16); den1 += __shfl_xor(den1, 32);
    if (lane < 16) {
        float* dp = den + ((size_t)js * NHD + h) * NN + i0 + rg * 32;
        dp[lane] = den0;
        dp[16 + lane] = den1;
    }
    // num partials (fp16): C/D row = q*4+reg (i-local), col = nt*16+m (f)
    #pragma unroll
    for (int g = 0; g < 2; ++g)
        #pragma unroll
        for (int nt = 0; nt < 8; ++nt)
            #pragma unroll
            for (int reg = 0; reg < 4; ++reg) {
                int i = i0 + rg * 32 + g * 16 + q * 4 + reg;
                num[((size_t)js * NN + i) * HF + h * OF + nt * 16 + m] =
                    (_Float16)acc[g][nt][reg];
            }
}

// ---------------- K4: reduce js partials, divide, +bias, fp32 out ---------
__global__ __launch_bounds__(256) void k_reduce(const _Float16* __restrict__ num,
                                                const float* __restrict__ den,
                                                const float* __restrict__ bias,
                                                float* __restrict__ out) {
    int g = blockIdx.x * 256 + threadIdx.x;    // NN*HF/4 groups
    int i = g >> 7, c4 = (g & 127) << 2;
    int h = c4 >> 7;
    float s0 = 0.f, s1 = 0.f, s2 = 0.f, s3 = 0.f, d = 0.f;
    #pragma unroll
    for (int js = 0; js < 4; ++js) {
        f16x4 v = *(const f16x4*)(num + ((size_t)js * NN + i) * HF + c4);
        s0 += (float)v[0]; s1 += (float)v[1]; s2 += (float)v[2]; s3 += (float)v[3];
        d += den[((size_t)js * NHD + h) * NN + i];
    }
    float inv = 1.0f / d;
    float4 b = *(const float4*)(bias + c4);
    float4 o;
    o.x = s0 * inv + b.x; o.y = s1 * inv + b.y;
    o.z = s2 * inv + b.z; o.w = s3 * inv + b.w;
    *(float4*)(out + (size_t)i * HF + c4) = o;
}

extern "C" void kernel_launch(void* const* d_in, const int* in_sizes, int n_in,
                              void* d_out, int out_size, void* d_ws, size_t ws_size,
                              hipStream_t stream) {
    const float* x    = (const float*)d_in[0];
    const float* adj  = (const float*)d_in[1];
    const float* W    = (const float*)d_in[2];
    const float* ai   = (const float*)d_in[3];
    const float* aj   = (const float*)d_in[4];
    const float* bias = (const float*)d_in[5];
    float* out = (float*)d_out;

    char* ws = (char*)d_ws;
    __bf16*   hbT = (__bf16*)(ws);                       // 4,259,840 B
    float*    ci  = (float*)(ws + 4456448);              // 64 KB
    float*    cj  = (float*)(ws + 4456448 + 65536);      // 64 KB
    float*    den = (float*)(ws + 4587520);              // 256 KB
    __bf16*   WT  = (__bf16*)(ws + 4980736);             // 256 KB
    _Float16* num = (_Float16*)(ws + 5242880);           // 16 MB -> ends ~20.25 MB

    k_transpose_w<<<dim3(4, 8), 256, 0, stream>>>(W, WT);
    k_gemm_h<<<256, 512, 0, stream>>>(x, WT, ai, aj, hbT, ci, cj);
    k_attn<<<256, 512, 0, stream>>>(adj, hbT, ci, cj, num, den);
    k_reduce<<<2048, 256, 0, stream>>>(num, den, bias, out);
}